// Round 5
// baseline (209.084 us; speedup 1.0000x reference)
//
#include <hip/hip_runtime.h>
#include <hip/hip_cooperative_groups.h>
#include <cstdint>

namespace cg = cooperative_groups;

#define NB   32
#define NGT  128
#define NL   8400
#define TK   9
#define NC   80
#define FEPS 1e-9f
#define NTILE 33          // ceil(NL/256)
#define GRID  256

typedef unsigned long long u64;

__device__ __forceinline__ float iou_box(float ax0, float ay0, float ax1, float ay1,
                                         float bx0, float by0, float bx1, float by1) {
#pragma clang fp contract(off)
    float lx = fmaxf(ax0, bx0), ly = fmaxf(ay0, by0);
    float rx = fminf(ax1, bx1), ry = fminf(ay1, by1);
    float w = fmaxf(rx - lx, 0.f), h = fmaxf(ry - ly, 0.f);
    float inter = w * h;
    float a1 = (ax1 - ax0) * (ay1 - ay0);
    float a2 = (bx1 - bx0) * (by1 - by0);
    float uni = a1 + a2 - inter + FEPS;
    return inter / uni;
}

// Decode global anchor index -> analytic box (exact: centers (i+0.5)*s, half=2.5*s;
// all values exactly representable in fp32 -> bit-identical to the input table).
__device__ __forceinline__ void anchor_box(int a, float& x0, float& y0, float& x1, float& y1) {
    int fs, rem; float s;
    if (a < 6400)      { fs = 80; s = 8.f;  rem = a; }
    else if (a < 8000) { fs = 40; s = 16.f; rem = a - 6400; }
    else               { fs = 20; s = 32.f; rem = a - 8000; }
    int iy = rem / fs, ix = rem - iy * fs;
    float cx = ((float)ix + 0.5f) * s, cy = ((float)iy + 0.5f) * s, h = 2.5f * s;
    x0 = cx - h; y0 = cy - h; x1 = cx + h; y1 = cy + h;
}

// Single cooperative kernel: phase 1 (blocks 0..63) = per-(gt,level) register-
// sorted top-9 over the provable 10x10 candidate window -> thr -> compact cand
// list; grid.sync(); phase 2 = grid-stride over (b, 256-anchor tile) assign.
__global__ void __launch_bounds__(256)
atss_fused_kernel(const int* __restrict__ gtl, const float* __restrict__ gtb,
                  const float* __restrict__ padm, const float* __restrict__ pred,
                  const int* __restrict__ bgp, int* __restrict__ cand,
                  float* __restrict__ out) {
#pragma clang fp contract(off)
    __shared__ float siou[64][27];
    __shared__ int   sidx[64][27];
    __shared__ unsigned int smask[256][4];
    __shared__ float4 sgt[NGT];
    __shared__ int    slbl[NGT];
    __shared__ int    s_lab[256];
    __shared__ float  s_iou[256];

    cg::grid_group grid = cg::this_grid();
    const int tid = threadIdx.x;

    // ---------------- phase 1: top-9 + threshold -> cand[(b*128+g)*27] ----------
    if (blockIdx.x < 64 && tid < 192) {
        const int gl = tid & 63;                 // gt within block
        const int lv = tid >> 6;                 // level 0..2
        const int p  = blockIdx.x * 64 + gl;     // global (b,g) pair

        const float4 gb = ((const float4*)gtb)[p];
        const float gx0 = gb.x, gy0 = gb.y, gx1 = gb.z, gy1 = gb.w;
        const float gcx = (gx0 + gx1) * 0.5f, gcy = (gy0 + gy1) * 0.5f;

        const int   fs   = (lv == 0) ? 80 : (lv == 1 ? 40 : 20);
        const float s    = (lv == 0) ? 8.f : (lv == 1 ? 16.f : 32.f);
        const int   base = (lv == 0) ? 0 : (lv == 1 ? 6400 : 8000);

        const int fx = (int)floorf(gcx / s - 0.5f);
        const int fy = (int)floorf(gcy / s - 0.5f);
        const int lox = min(max(fx - 4, 0), fs - 10);
        const int loy = min(max(fy - 4, 0), fs - 10);

        u64 sk[TK];
#pragma unroll
        for (int j = 0; j < TK; ++j) sk[j] = ~0ULL;

        for (int r = 0; r < 10; ++r) {
            const int iy = loy + r;
            const float ay = ((float)iy + 0.5f) * s;
            const float dy = gcy - ay;
            const float dy2 = dy * dy;
            const int rowbase = base + iy * fs + lox;
#pragma unroll
            for (int c = 0; c < 10; ++c) {
                const float ax = ((float)(lox + c) + 0.5f) * s;
                const float dx = gcx - ax;
                const float d = sqrtf(dx * dx + dy2);
                u64 nk = ((u64)__float_as_uint(d) << 32) | (unsigned int)(rowbase + c);
                // branchless sorted insert (ascending), max expelled
#pragma unroll
                for (int j = 0; j < TK; ++j) {
                    const u64 sj = sk[j];
                    const u64 mn = (nk < sj) ? nk : sj;
                    nk = (nk < sj) ? sj : nk;
                    sk[j] = mn;
                }
            }
        }
        // 9 IoUs (order = ascending (d,idx), identical to lax.top_k output order)
#pragma unroll
        for (int j = 0; j < TK; ++j) {
            const int id = (int)(unsigned int)(sk[j] & 0xffffffffu);
            float ax0, ay0, ax1, ay1;
            anchor_box(id, ax0, ay0, ax1, ay1);
            siou[gl][lv * TK + j] = iou_box(gx0, gy0, gx1, gy1, ax0, ay0, ax1, ay1);
            sidx[gl][lv * TK + j] = id;
        }
    }
    __syncthreads();
    if (blockIdx.x < 64 && tid < 64) {
        const int p = blockIdx.x * 64 + tid;
        int* cp = cand + (size_t)p * 27;
        if (padm[p] <= 0.f) {
#pragma unroll
            for (int k = 0; k < 27; ++k) cp[k] = -1;
        } else {
            const float4 gb = ((const float4*)gtb)[p];
            const float gx0 = gb.x, gy0 = gb.y, gx1 = gb.z, gy1 = gb.w;
            float sum = 0.f;
#pragma unroll
            for (int k = 0; k < 27; ++k) sum += siou[tid][k];
            const float mean = sum / 27.f;
            float d2 = 0.f;
#pragma unroll
            for (int k = 0; k < 27; ++k) {
                const float e = siou[tid][k] - mean;
                d2 += e * e;
            }
            const float thr = mean + sqrtf(d2 / 26.f);   // ddof=1 -> /26
#pragma unroll
            for (int k = 0; k < 27; ++k) {
                const int id = sidx[tid][k];
                int keep = -1;
                if (siou[tid][k] > thr) {
                    float ax0, ay0, ax1, ay1;
                    anchor_box(id, ax0, ay0, ax1, ay1);
                    const float acx = (ax0 + ax1) * 0.5f, acy = (ay0 + ay1) * 0.5f;
                    const float l = acx - gx0, t = acy - gy0, r = gx1 - acx, bo = gy1 - acy;
                    const float mn = fminf(fminf(l, t), fminf(r, bo));
                    if (mn > FEPS) keep = id;
                }
                cp[k] = keep;
            }
        }
    }

    grid.sync();

    // ---------------- phase 2: assign, grid-stride over (b, tile) ---------------
    const int bgi = *bgp;
    for (int vb = blockIdx.x; vb < NB * NTILE; vb += GRID) {
        const int b = vb / NTILE;
        const int a0 = (vb - b * NTILE) * 256;
        const int nA = min(256, NL - a0);

        smask[tid][0] = 0; smask[tid][1] = 0; smask[tid][2] = 0; smask[tid][3] = 0;
        if (tid < NGT) {
            sgt[tid]  = ((const float4*)gtb)[b * NGT + tid];
            slbl[tid] = gtl[b * NGT + tid];
        }
        __syncthreads();

        // scatter this batch's candidate entries into the LDS bitmask
        const int* cb = cand + (size_t)b * NGT * 27;
        for (int f = tid; f < NGT * 27; f += 256) {
            const int id = cb[f];
            const int la = id - a0;
            if (la >= 0 && la < nA) {
                const int g = f / 27;
                atomicOr(&smask[la][g >> 5], 1u << (g & 31));
            }
        }
        __syncthreads();

        int lbl = 0, pos = 0;
        float ioup = 0.f;
        const int a = a0 + tid;
        if (a < NL) {
            const int t = b * NL + a;
            const unsigned int m0 = smask[tid][0], m1 = smask[tid][1];
            const unsigned int m2 = smask[tid][2], m3 = smask[tid][3];
            const int mps = __popc(m0) + __popc(m1) + __popc(m2) + __popc(m3);
            int agi = 0;
            if (mps > 1) {
                // reference: replaced by one-hot argmax over ALL gts (incl. padded)
                float ax0, ay0, ax1, ay1;
                anchor_box(a, ax0, ay0, ax1, ay1);
                float best = -1.f;
                for (int gg = 0; gg < NGT; ++gg) {
                    const float4 q = sgt[gg];
                    const float v = iou_box(q.x, q.y, q.z, q.w, ax0, ay0, ax1, ay1);
                    if (v > best) { best = v; agi = gg; }   // strict > keeps first max
                }
                pos = 1;
            } else if (mps == 1) {
                if (m0)      agi = __ffs(m0) - 1;
                else if (m1) agi = 32 + __ffs(m1) - 1;
                else if (m2) agi = 64 + __ffs(m2) - 1;
                else         agi = 96 + __ffs(m3) - 1;
                pos = 1;
            }
            lbl = pos ? slbl[agi] : bgi;
            out[t] = (float)lbl;

            const float4 q = sgt[agi];
            ((float4*)(out + (size_t)NB * NL))[t] = q;

            if (pos) {
                const float4 pb = ((const float4*)pred)[t];
                ioup = iou_box(q.x, q.y, q.z, q.w, pb.x, pb.y, pb.z, pb.w);
            }
        }
        s_lab[tid] = pos ? lbl : -1;
        s_iou[tid] = ioup;
        __syncthreads();

        // scores: (nA anchors) x 80 classes, float4 stores (20 per anchor)
        float4* osb = (float4*)(out + (size_t)NB * NL * 5 + ((size_t)b * NL + a0) * NC);
        const int total4 = nA * (NC / 4);
        for (int e = tid; e < total4; e += 256) {
            const int ai = e / (NC / 4);
            const int c0 = (e - ai * (NC / 4)) * 4;
            const int lb = s_lab[ai];
            const float v = s_iou[ai];
            float4 o;
            o.x = (c0     == lb) ? v : 0.f;
            o.y = (c0 + 1 == lb) ? v : 0.f;
            o.z = (c0 + 2 == lb) ? v : 0.f;
            o.w = (c0 + 3 == lb) ? v : 0.f;
            osb[e] = o;
        }
        __syncthreads();   // protect LDS reuse in next grid-stride iteration
    }
}

extern "C" void kernel_launch(void* const* d_in, const int* in_sizes, int n_in,
                              void* d_out, int out_size, void* d_ws, size_t ws_size,
                              hipStream_t stream) {
    const int*   gtl  = (const int*)d_in[1];     // (32,128,1)
    const float* gtb  = (const float*)d_in[2];   // (32,128,4)
    const float* padm = (const float*)d_in[3];   // (32,128,1)
    const float* pred = (const float*)d_in[4];   // (32,8400,4)
    const int*   bgp  = (const int*)d_in[5];     // scalar
    int*         cand = (int*)d_ws;              // (B*NGT, 27), fully overwritten
    float*       out  = (float*)d_out;

    void* args[] = {(void*)&gtl, (void*)&gtb, (void*)&padm, (void*)&pred,
                    (void*)&bgp, (void*)&cand, (void*)&out};
    (void)hipLaunchCooperativeKernel((const void*)atss_fused_kernel,
                                     dim3(GRID), dim3(256), args, 0, stream);
}

// Round 6
// 164.591 us; speedup vs baseline: 1.2703x; 1.2703x over previous
//
#include <hip/hip_runtime.h>
#include <cstdint>

#define NB    32
#define NGT   128
#define NL    8400
#define TK    9
#define NC    80
#define FEPS  1e-9f
#define NTILE 33          // ceil(NL/256)

typedef unsigned long long u64;

__device__ __forceinline__ float iou_box(float ax0, float ay0, float ax1, float ay1,
                                         float bx0, float by0, float bx1, float by1) {
#pragma clang fp contract(off)
    float lx = fmaxf(ax0, bx0), ly = fmaxf(ay0, by0);
    float rx = fminf(ax1, bx1), ry = fminf(ay1, by1);
    float w = fmaxf(rx - lx, 0.f), h = fmaxf(ry - ly, 0.f);
    float inter = w * h;
    float a1 = (ax1 - ax0) * (ay1 - ay0);
    float a2 = (bx1 - bx0) * (by1 - by0);
    float uni = a1 + a2 - inter + FEPS;
    return inter / uni;
}

// Decode global anchor index -> analytic box (exact: centers (i+0.5)*s, half=2.5*s;
// all values exactly representable in fp32 -> bit-identical to the input table).
__device__ __forceinline__ void anchor_box(int a, float& x0, float& y0, float& x1, float& y1) {
    int fs, rem; float s;
    if (a < 6400)      { fs = 80; s = 8.f;  rem = a; }
    else if (a < 8000) { fs = 40; s = 16.f; rem = a - 6400; }
    else               { fs = 20; s = 32.f; rem = a - 8000; }
    int iy = rem / fs, ix = rem - iy * fs;
    float cx = ((float)ix + 0.5f) * s, cy = ((float)iy + 0.5f) * s, h = 2.5f * s;
    x0 = cx - h; y0 = cy - h; x1 = cx + h; y1 = cy + h;
}

// Single regular dispatch, grid (33,32): block = (256-anchor tile, batch b).
// Phase A: block redundantly computes batch-b topk: 384 (gt,level) tasks, each a
//   branchless register-sorted top-9 of packed (dist_bits<<32)|idx u64 keys over
//   the 5x5 window centered on the nearest grid cell (provably contains all
//   points with d <= d9: d9 <= sqrt(2)*1.5s from the nearest-3x3 block, while
//   everything outside the 5x5 is >= 2.5s away; edge clamps only widen the gap).
// Phase B: per-gt threshold mean+std(ddof=1) -> 27-bit keep mask.
// Phase C: scatter kept candidates into per-anchor LDS gt-bitmask.
// Phase D/E: resolve assignment, write labels/bboxes/scores coalesced.
__global__ void __launch_bounds__(256)
atss_fused(const int* __restrict__ gtl, const float* __restrict__ gtb,
           const float* __restrict__ padm, const float* __restrict__ pred,
           const int* __restrict__ bgp, float* __restrict__ out) {
#pragma clang fp contract(off)
    __shared__ float4        sgt[NGT];         // gt boxes
    __shared__ int           slbl[NGT];        // gt labels
    __shared__ float         siou[NGT][27];    // iou of gt vs its 27 candidates
    __shared__ unsigned short sidx[NGT][27];   // candidate anchor ids (<8400)
    __shared__ unsigned int  skeep[NGT];       // 27-bit keep mask per gt
    __shared__ unsigned int  smask[256][4];    // per-anchor gt bitmask
    __shared__ int           s_lab[256];
    __shared__ float         s_sco[256];

    const int tid = threadIdx.x;
    const int b   = blockIdx.y;
    const int a0  = blockIdx.x * 256;
    const int nA  = min(256, NL - a0);
    const int a   = a0 + tid;
    const int t   = b * NL + a;
    const int bgi = *bgp;

    // early independent global loads (latency hidden behind phase A VALU)
    float4 pb;
    if (a < NL) pb = ((const float4*)pred)[t];
    if (tid < NGT) {
        sgt[tid]  = ((const float4*)gtb)[b * NGT + tid];
        slbl[tid] = gtl[b * NGT + tid];
    }
    smask[tid][0] = 0; smask[tid][1] = 0; smask[tid][2] = 0; smask[tid][3] = 0;
    __syncthreads();

    // ---- phase A: top-9 per (gt, level) --------------------------------------
    for (int task = tid; task < NGT * 3; task += 256) {
        const int g  = task & (NGT - 1);
        const int lv = task >> 7;
        const float4 gb = sgt[g];
        const float gx0 = gb.x, gy0 = gb.y, gx1 = gb.z, gy1 = gb.w;
        const float gcx = (gx0 + gx1) * 0.5f, gcy = (gy0 + gy1) * 0.5f;

        const int   fs   = (lv == 0) ? 80 : (lv == 1 ? 40 : 20);
        const float s    = (lv == 0) ? 8.f : (lv == 1 ? 16.f : 32.f);
        const int   base = (lv == 0) ? 0 : (lv == 1 ? 6400 : 8000);

        // nearest cell (gcx/s exact: s is a power of two), 5x5 window clamped
        const int nx = min(max((int)floorf(gcx / s), 0), fs - 1);
        const int ny = min(max((int)floorf(gcy / s), 0), fs - 1);
        const int lox = min(max(nx - 2, 0), fs - 5);
        const int loy = min(max(ny - 2, 0), fs - 5);

        u64 sk[TK];
#pragma unroll
        for (int j = 0; j < TK; ++j) sk[j] = ~0ULL;

#pragma unroll
        for (int r = 0; r < 5; ++r) {
            const int iy = loy + r;
            const float ay = ((float)iy + 0.5f) * s;
            const float dy = gcy - ay;
            const float dy2 = dy * dy;
            const int rowbase = base + iy * fs + lox;
#pragma unroll
            for (int c = 0; c < 5; ++c) {
                const float ax = ((float)(lox + c) + 0.5f) * s;
                const float dx = gcx - ax;
                const float d = sqrtf(dx * dx + dy2);
                u64 nk = ((u64)__float_as_uint(d) << 32) | (unsigned int)(rowbase + c);
                // branchless sorted insert (ascending), max expelled
#pragma unroll
                for (int j = 0; j < TK; ++j) {
                    const u64 sj = sk[j];
                    const u64 mn = (nk < sj) ? nk : sj;
                    nk = (nk < sj) ? sj : nk;
                    sk[j] = mn;
                }
            }
        }
        // order = ascending (d, idx) == lax.top_k output order
#pragma unroll
        for (int j = 0; j < TK; ++j) {
            const int id = (int)(unsigned int)(sk[j] & 0xffffffffu);
            float ax0, ay0, ax1, ay1;
            anchor_box(id, ax0, ay0, ax1, ay1);
            siou[g][lv * TK + j] = iou_box(gx0, gy0, gx1, gy1, ax0, ay0, ax1, ay1);
            sidx[g][lv * TK + j] = (unsigned short)id;
        }
    }
    __syncthreads();

    // ---- phase B: threshold + keep mask per gt -------------------------------
    if (tid < NGT) {
        unsigned int keep = 0;
        if (padm[b * NGT + tid] > 0.f) {
            const float4 gb = sgt[tid];
            const float gx0 = gb.x, gy0 = gb.y, gx1 = gb.z, gy1 = gb.w;
            float sum = 0.f;
#pragma unroll
            for (int k = 0; k < 27; ++k) sum += siou[tid][k];
            const float mean = sum / 27.f;
            float d2 = 0.f;
#pragma unroll
            for (int k = 0; k < 27; ++k) {
                const float e = siou[tid][k] - mean;
                d2 += e * e;
            }
            const float thr = mean + sqrtf(d2 / 26.f);   // ddof=1 -> /26
#pragma unroll
            for (int k = 0; k < 27; ++k) {
                if (siou[tid][k] > thr) {
                    float ax0, ay0, ax1, ay1;
                    anchor_box((int)sidx[tid][k], ax0, ay0, ax1, ay1);
                    const float acx = (ax0 + ax1) * 0.5f, acy = (ay0 + ay1) * 0.5f;
                    const float l = acx - gx0, tt = acy - gy0;
                    const float r = gx1 - acx, bo = gy1 - acy;
                    const float mn = fminf(fminf(l, tt), fminf(r, bo));
                    if (mn > FEPS) keep |= (1u << k);
                }
            }
        }
        skeep[tid] = keep;
    }
    __syncthreads();

    // ---- phase C: scatter kept candidates into per-anchor bitmask ------------
    for (int f = tid; f < NGT * 27; f += 256) {
        const int g = f / 27;
        const int k = f - g * 27;
        if ((skeep[g] >> k) & 1u) {
            const int la = (int)sidx[g][k] - a0;
            if (la >= 0 && la < nA) {
                atomicOr(&smask[la][g >> 5], 1u << (g & 31));
            }
        }
    }
    __syncthreads();

    // ---- phase D: resolve assignment per anchor ------------------------------
    int lbl = 0, pos = 0;
    float ioup = 0.f;
    if (a < NL) {
        const unsigned int m0 = smask[tid][0], m1 = smask[tid][1];
        const unsigned int m2 = smask[tid][2], m3 = smask[tid][3];
        const int mps = __popc(m0) + __popc(m1) + __popc(m2) + __popc(m3);
        int agi = 0;
        if (mps > 1) {
            // reference: replaced by one-hot argmax over ALL gts (incl. padded)
            float ax0, ay0, ax1, ay1;
            anchor_box(a, ax0, ay0, ax1, ay1);
            float best = -1.f;
            for (int gg = 0; gg < NGT; ++gg) {
                const float4 q = sgt[gg];
                const float v = iou_box(q.x, q.y, q.z, q.w, ax0, ay0, ax1, ay1);
                if (v > best) { best = v; agi = gg; }   // strict > keeps first max
            }
            pos = 1;
        } else if (mps == 1) {
            if (m0)      agi = __ffs(m0) - 1;
            else if (m1) agi = 32 + __ffs(m1) - 1;
            else if (m2) agi = 64 + __ffs(m2) - 1;
            else         agi = 96 + __ffs(m3) - 1;
            pos = 1;
        }
        lbl = pos ? slbl[agi] : bgi;
        out[t] = (float)lbl;

        const float4 q = sgt[agi];
        ((float4*)(out + (size_t)NB * NL))[t] = q;

        if (pos) ioup = iou_box(q.x, q.y, q.z, q.w, pb.x, pb.y, pb.z, pb.w);
    }
    s_lab[tid] = pos ? lbl : -1;
    s_sco[tid] = ioup;
    __syncthreads();

    // ---- phase E: scores (nA anchors x 80 classes), float4 coalesced ---------
    float4* osb = (float4*)(out + (size_t)NB * NL * 5 + ((size_t)b * NL + a0) * NC);
    const int total4 = nA * (NC / 4);
    for (int e = tid; e < total4; e += 256) {
        const int ai = e / (NC / 4);
        const int c0 = (e - ai * (NC / 4)) * 4;
        const int lb = s_lab[ai];
        const float v = s_sco[ai];
        float4 o;
        o.x = (c0     == lb) ? v : 0.f;
        o.y = (c0 + 1 == lb) ? v : 0.f;
        o.z = (c0 + 2 == lb) ? v : 0.f;
        o.w = (c0 + 3 == lb) ? v : 0.f;
        osb[e] = o;
    }
}

extern "C" void kernel_launch(void* const* d_in, const int* in_sizes, int n_in,
                              void* d_out, int out_size, void* d_ws, size_t ws_size,
                              hipStream_t stream) {
    const int*   gtl  = (const int*)d_in[1];     // (32,128,1)
    const float* gtb  = (const float*)d_in[2];   // (32,128,4)
    const float* padm = (const float*)d_in[3];   // (32,128,1)
    const float* pred = (const float*)d_in[4];   // (32,8400,4)
    const int*   bgp  = (const int*)d_in[5];     // scalar

    dim3 grid(NTILE, NB);
    atss_fused<<<grid, 256, 0, stream>>>(gtl, gtb, padm, pred, bgp, (float*)d_out);
}

// Round 7
// 137.167 us; speedup vs baseline: 1.5243x; 1.1999x over previous
//
#include <hip/hip_runtime.h>
#include <cstdint>

#define NB   32
#define NGT  128
#define NL   8400
#define TK   9
#define NC   80
#define FEPS 1e-9f

typedef unsigned long long u64;

__device__ __forceinline__ float iou_box(float ax0, float ay0, float ax1, float ay1,
                                         float bx0, float by0, float bx1, float by1) {
#pragma clang fp contract(off)
    float lx = fmaxf(ax0, bx0), ly = fmaxf(ay0, by0);
    float rx = fminf(ax1, bx1), ry = fminf(ay1, by1);
    float w = fmaxf(rx - lx, 0.f), h = fmaxf(ry - ly, 0.f);
    float inter = w * h;
    float a1 = (ax1 - ax0) * (ay1 - ay0);
    float a2 = (bx1 - bx0) * (by1 - by0);
    float uni = a1 + a2 - inter + FEPS;
    return inter / uni;
}

// Decode global anchor index -> analytic box (exact: centers (i+0.5)*s, half=2.5*s;
// all values exactly representable in fp32 -> bit-identical to the input table).
__device__ __forceinline__ void anchor_box(int a, float& x0, float& y0, float& x1, float& y1) {
    int fs, rem; float s;
    if (a < 6400)      { fs = 80; s = 8.f;  rem = a; }
    else if (a < 8000) { fs = 40; s = 16.f; rem = a - 6400; }
    else               { fs = 20; s = 32.f; rem = a - 8000; }
    int iy = rem / fs, ix = rem - iy * fs;
    float cx = ((float)ix + 0.5f) * s, cy = ((float)iy + 0.5f) * s, h = 2.5f * s;
    x0 = cx - h; y0 = cy - h; x1 = cx + h; y1 = cy + h;
}

// Block = 192 threads = 64 gts x 3 levels. Thread (gt,level) scans the 5x5
// candidate window centered on the nearest grid cell (provably contains the 9
// nearest grid anchors: d9 <= sqrt(2)*1.5s via the nearest-3x3 block, anything
// outside the 5x5 is >= 2.5s away; edge clamps only widen the gap — verified
// bit-identical vs the 10x10 window in R6, absmax 0). Branchless register-
// sorted top-9 of packed (dist_bits<<32)|idx u64 keys; IoUs -> LDS; thread
// gt (<64) computes thr = mean+std(ddof=1) and writes passed anchor ids
// (or -1) to cand[(b*128+g)*27 + k]. Every slot written -> no zero-init.
__global__ void __launch_bounds__(192)
atss_topk_kernel(const float* __restrict__ gtb, const float* __restrict__ padm,
                 int* __restrict__ cand) {
#pragma clang fp contract(off)
    __shared__ float siou[64][27];
    __shared__ int   sidx[64][27];

    const int tid = threadIdx.x;
    const int gl  = tid & 63;           // gt within block
    const int lv  = tid >> 6;           // level 0..2
    const int p   = blockIdx.x * 64 + gl;  // global (b,g) pair

    const float4 gb = ((const float4*)gtb)[p];
    const float gx0 = gb.x, gy0 = gb.y, gx1 = gb.z, gy1 = gb.w;
    const float gcx = (gx0 + gx1) * 0.5f, gcy = (gy0 + gy1) * 0.5f;

    {
        const int   fs   = (lv == 0) ? 80 : (lv == 1 ? 40 : 20);
        const float s    = (lv == 0) ? 8.f : (lv == 1 ? 16.f : 32.f);
        const int   base = (lv == 0) ? 0 : (lv == 1 ? 6400 : 8000);

        const int nx = min(max((int)floorf(gcx / s), 0), fs - 1);
        const int ny = min(max((int)floorf(gcy / s), 0), fs - 1);
        const int lox = min(max(nx - 2, 0), fs - 5);
        const int loy = min(max(ny - 2, 0), fs - 5);

        u64 sk[TK];
#pragma unroll
        for (int j = 0; j < TK; ++j) sk[j] = ~0ULL;

#pragma unroll
        for (int r = 0; r < 5; ++r) {
            const int iy = loy + r;
            const float ay = ((float)iy + 0.5f) * s;
            const float dy = gcy - ay;
            const float dy2 = dy * dy;
            const int rowbase = base + iy * fs + lox;
#pragma unroll
            for (int c = 0; c < 5; ++c) {
                const float ax = ((float)(lox + c) + 0.5f) * s;
                const float dx = gcx - ax;
                const float d = sqrtf(dx * dx + dy2);
                u64 nk = ((u64)__float_as_uint(d) << 32) | (unsigned int)(rowbase + c);
                // branchless sorted insert (ascending), max expelled
#pragma unroll
                for (int j = 0; j < TK; ++j) {
                    const u64 sj = sk[j];
                    const u64 mn = (nk < sj) ? nk : sj;
                    nk = (nk < sj) ? sj : nk;
                    sk[j] = mn;
                }
            }
        }

        // order = ascending (d, idx) == lax.top_k output order
#pragma unroll
        for (int j = 0; j < TK; ++j) {
            const int id = (int)(unsigned int)(sk[j] & 0xffffffffu);
            float ax0, ay0, ax1, ay1;
            anchor_box(id, ax0, ay0, ax1, ay1);
            siou[gl][lv * TK + j] = iou_box(gx0, gy0, gx1, gy1, ax0, ay0, ax1, ay1);
            sidx[gl][lv * TK + j] = id;
        }
    }
    __syncthreads();

    if (tid < 64) {
        int* cp = cand + (size_t)p * 27;
        if (padm[p] <= 0.f) {
#pragma unroll
            for (int k = 0; k < 27; ++k) cp[k] = -1;
            return;
        }
        float sum = 0.f;
#pragma unroll
        for (int k = 0; k < 27; ++k) sum += siou[gl][k];
        const float mean = sum / 27.f;
        float d2 = 0.f;
#pragma unroll
        for (int k = 0; k < 27; ++k) {
            const float e = siou[gl][k] - mean;
            d2 += e * e;
        }
        const float thr = mean + sqrtf(d2 / 26.f);   // ddof=1 -> /26

#pragma unroll
        for (int k = 0; k < 27; ++k) {
            const int id = sidx[gl][k];
            int keep = -1;
            if (siou[gl][k] > thr) {
                float ax0, ay0, ax1, ay1;
                anchor_box(id, ax0, ay0, ax1, ay1);
                const float acx = (ax0 + ax1) * 0.5f, acy = (ay0 + ay1) * 0.5f;
                const float l = acx - gx0, t = acy - gy0, r = gx1 - acx, bo = gy1 - acy;
                const float mn = fminf(fminf(l, t), fminf(r, bo));
                if (mn > FEPS) keep = id;
            }
            cp[k] = keep;
        }
    }
}

// Block = (256 anchors, b). Builds the per-anchor gt bitmask in LDS from the
// batch's 128*27 candidate entries, then resolves assignment and writes
// labels/bboxes/scores with fully-coalesced (float4 for scores) stores.
// (Byte-identical to the R4 kernel that passed with absmax 0.)
__global__ void __launch_bounds__(256)
atss_assign_kernel(const int* __restrict__ gtl, const float* __restrict__ gtb,
                   const float* __restrict__ pred, const int* __restrict__ bgp,
                   const int* __restrict__ cand, float* __restrict__ out) {
#pragma clang fp contract(off)
    __shared__ unsigned int smask[256][4];
    __shared__ float4 sgt[NGT];
    __shared__ int    slbl[NGT];
    __shared__ int    s_lab[256];
    __shared__ float  s_iou[256];

    const int tid = threadIdx.x;
    const int b = blockIdx.y;
    const int a0 = blockIdx.x * 256;
    const int nA = min(256, NL - a0);

    smask[tid][0] = 0; smask[tid][1] = 0; smask[tid][2] = 0; smask[tid][3] = 0;
    if (tid < NGT) {
        sgt[tid]  = ((const float4*)gtb)[b * NGT + tid];
        slbl[tid] = gtl[b * NGT + tid];
    }
    __syncthreads();

    // scatter candidate entries for this batch into the LDS bitmask
    const int* cb = cand + (size_t)b * NGT * 27;
    for (int f = tid; f < NGT * 27; f += 256) {
        const int id = cb[f];
        const int la = id - a0;
        if (la >= 0 && la < nA) {
            const int g = f / 27;
            atomicOr(&smask[la][g >> 5], 1u << (g & 31));
        }
    }
    __syncthreads();

    int lbl = 0, pos = 0;
    float ioup = 0.f;
    const int a = a0 + tid;
    if (a < NL) {
        const int t = b * NL + a;
        const unsigned int m0 = smask[tid][0], m1 = smask[tid][1];
        const unsigned int m2 = smask[tid][2], m3 = smask[tid][3];
        const int mps = __popc(m0) + __popc(m1) + __popc(m2) + __popc(m3);
        int agi = 0;
        if (mps > 1) {
            // reference: replaced by one-hot argmax over ALL gts (incl. padded)
            float ax0, ay0, ax1, ay1;
            anchor_box(a, ax0, ay0, ax1, ay1);
            float best = -1.f;
            for (int gg = 0; gg < NGT; ++gg) {
                const float4 q = sgt[gg];
                const float v = iou_box(q.x, q.y, q.z, q.w, ax0, ay0, ax1, ay1);
                if (v > best) { best = v; agi = gg; }   // strict > keeps first max
            }
            pos = 1;
        } else if (mps == 1) {
            if (m0)      agi = __ffs(m0) - 1;
            else if (m1) agi = 32 + __ffs(m1) - 1;
            else if (m2) agi = 64 + __ffs(m2) - 1;
            else         agi = 96 + __ffs(m3) - 1;
            pos = 1;
        }
        const int bgi = *bgp;
        lbl = pos ? slbl[agi] : bgi;
        out[t] = (float)lbl;

        const float4 q = sgt[agi];
        ((float4*)(out + (size_t)NB * NL))[t] = q;

        if (pos) {
            const float4 pb = ((const float4*)pred)[t];
            ioup = iou_box(q.x, q.y, q.z, q.w, pb.x, pb.y, pb.z, pb.w);
        }
    }
    s_lab[tid] = pos ? lbl : -1;
    s_iou[tid] = ioup;
    __syncthreads();

    // scores: (nA anchors) x 80 classes, written as float4 (20 per anchor)
    float4* osb = (float4*)(out + (size_t)NB * NL * 5 + ((size_t)b * NL + a0) * NC);
    const int total4 = nA * (NC / 4);
    for (int e = tid; e < total4; e += 256) {
        const int ai = e / (NC / 4);
        const int c0 = (e - ai * (NC / 4)) * 4;
        const int lb = s_lab[ai];
        const float v = s_iou[ai];
        float4 o;
        o.x = (c0     == lb) ? v : 0.f;
        o.y = (c0 + 1 == lb) ? v : 0.f;
        o.z = (c0 + 2 == lb) ? v : 0.f;
        o.w = (c0 + 3 == lb) ? v : 0.f;
        osb[e] = o;
    }
}

extern "C" void kernel_launch(void* const* d_in, const int* in_sizes, int n_in,
                              void* d_out, int out_size, void* d_ws, size_t ws_size,
                              hipStream_t stream) {
    const int*   gtl  = (const int*)d_in[1];     // (32,128,1)
    const float* gtb  = (const float*)d_in[2];   // (32,128,4)
    const float* padm = (const float*)d_in[3];   // (32,128,1)
    const float* pred = (const float*)d_in[4];   // (32,8400,4)
    const int*   bgp  = (const int*)d_in[5];     // scalar

    int* cand = (int*)d_ws;   // (B*NGT, 27) anchor id or -1; fully overwritten

    atss_topk_kernel<<<NB * NGT / 64, 192, 0, stream>>>(gtb, padm, cand);

    dim3 grid((NL + 255) / 256, NB);
    atss_assign_kernel<<<grid, 256, 0, stream>>>(gtl, gtb, pred, bgp, cand, (float*)d_out);
}